// Round 1
// baseline (110.882 us; speedup 1.0000x reference)
//
#include <hip/hip_runtime.h>
#include <math.h>

// Chamfer loss, B=4, C=3, Np=Ng=8192, fp32 — single dispatch.
// Round 5: latency attack. (1) YSPLITS 32->64: 2048 wgs = 8192 waves, full
// machine subscription (was 4096 waves / 25% occupancy). (2) depth-2 register
// pipeline on the uniform ds_read_b128 y-tile reads (pad ytile, prefetch jj+2
// before computing jj) so the ~120cy LDS latency hides under 2 iterations of
// packed FMA issue. Inner loop unchanged: 3 pk_fma + 1 min3 per 2 pairs.
// Cross-block combine identical (atomicMin on uint bit-pattern, 0xAA poison
// as +inf / ticket base; no init dispatch).

#define B_       4
#define N_       8192
#define THREADS  256
#define RX       8
#define XB       (THREADS * RX)        // 2048 x-points per workgroup
#define XBLKS    (N_ / XB)             // 4
#define YSPLITS  64
#define YCHUNK   (N_ / YSPLITS)        // 128 y-points per workgroup
#define NGROUPS  (2 * B_ * XBLKS)      // 32
#define POISON   0xAAAAAAAAu

typedef float v2f __attribute__((ext_vector_type(2)));

__device__ __forceinline__ v2f pk_fma(v2f a, v2f b, v2f c) {
    v2f d;
    asm("v_pk_fma_f32 %0, %1, %2, %3" : "=v"(d) : "v"(a), "v"(b), "v"(c));
    return d;
}

// ws layout (32-bit words):
//   [0, 65536)      mins (uint bit patterns; 0xAAAAAAAA acts as +inf)
//   [65536, 65568)  gcnt (per-group tickets, poison base)
//   [65600]         fcnt (final ticket, poison base)
//   [65664, 65696)  gsum (float group sums, fully overwritten)

__global__ __launch_bounds__(THREADS)
void chamfer_fused_kernel(const float* __restrict__ P, const float* __restrict__ G,
                          unsigned* __restrict__ mins, unsigned* __restrict__ gcnt,
                          unsigned* __restrict__ fcnt, float* __restrict__ gsum,
                          float* __restrict__ out)
{
    __shared__ float4 ytile[2 * (YCHUNK / 2) + 4];   // +4 pad slots for prefetch
    __shared__ float red[THREADS];
    __shared__ unsigned s_ticket;

    const int t      = threadIdx.x;
    const int xblk   = blockIdx.x;     // 0..3
    const int ysplit = blockIdx.y;     // 0..63
    const int bz     = blockIdx.z;     // 0..7
    const int pass   = bz >> 2;        // 0: X=predict, 1: X=gt
    const int b      = bz & 3;
    const int gid    = bz * XBLKS + xblk;   // 0..31

    const float* Xb = (pass ? G : P) + (size_t)b * 3 * N_;
    const float* Yb = (pass ? P : G) + (size_t)b * 3 * N_;

    // Stage y-pairs: slot 2*jj = (gx0,gx1,gy0,gy1), 2*jj+1 = (gz0,gz1,g2_0,g2_1)
    const int ybase = ysplit * YCHUNK;
    if (t < YCHUNK / 2) {
        const int n0 = ybase + 2 * t;
        float2 x01 = *(const float2*)&Yb[n0];
        float2 y01 = *(const float2*)&Yb[N_ + n0];
        float2 z01 = *(const float2*)&Yb[2 * N_ + n0];
        float w0 = fmaf(x01.x, x01.x, fmaf(y01.x, y01.x, z01.x * z01.x));
        float w1 = fmaf(x01.y, x01.y, fmaf(y01.y, y01.y, z01.y * z01.y));
        ytile[2 * t]     = make_float4(x01.x, x01.y, y01.x, y01.y);
        ytile[2 * t + 1] = make_float4(z01.x, z01.y, w0, w1);
    }

    // RX x-points per thread; -2*coord duplicated into both float2 halves.
    const int xbase = xblk * XB;
    v2f m2x2[RX], m2y2[RX], m2z2[RX];
    float p2[RX], mn[RX];
#pragma unroll
    for (int r = 0; r < RX; ++r) {
        const int n = xbase + r * THREADS + t;
        float px = Xb[n];
        float py = Xb[N_ + n];
        float pz = Xb[2 * N_ + n];
        p2[r]   = fmaf(px, px, fmaf(py, py, pz * pz));
        float ax = -2.0f * px, ay = -2.0f * py, az = -2.0f * pz;
        m2x2[r] = (v2f){ax, ax};
        m2y2[r] = (v2f){ay, ay};
        m2z2[r] = (v2f){az, az};
        mn[r]   = 3.4e38f;
    }
    __syncthreads();

    // Sweep with depth-2 register pipeline: compute jj from (a0,b0) while the
    // ds_read for jj+2 is in flight. Pad slots make the tail reads in-bounds
    // (values rotated in but never computed on).
    float4 a0 = ytile[0], b0 = ytile[1];
    float4 a1 = ytile[2], b1 = ytile[3];
#pragma unroll 2
    for (int jj = 0; jj < YCHUNK / 2; ++jj) {
        float4 an = ytile[2 * jj + 4];
        float4 bn = ytile[2 * jj + 5];
        v2f gx2 = (v2f){a0.x, a0.y};
        v2f gy2 = (v2f){a0.z, a0.w};
        v2f gz2 = (v2f){b0.x, b0.y};
        v2f gw2 = (v2f){b0.z, b0.w};
#pragma unroll
        for (int r = 0; r < RX; ++r) {
            v2f s = pk_fma(m2z2[r], gz2, gw2);
            s = pk_fma(m2y2[r], gy2, s);
            s = pk_fma(m2x2[r], gx2, s);
            mn[r] = fminf(fminf(mn[r], s.x), s.y);   // -> v_min3_f32
        }
        a0 = a1; b0 = b1; a1 = an; b1 = bn;
    }

    // Publish clamped d2 = mn + p2 (>= 1e-12 > 0: uint order == float order).
    unsigned* mybase = mins + (size_t)(pass * B_ + b) * N_ + xbase;
#pragma unroll
    for (int r = 0; r < RX; ++r) {
        float v = fmaxf(mn[r] + p2[r], 1e-12f);
        atomicMin(&mybase[r * THREADS + t], __float_as_uint(v));
    }

    __syncthreads();
    if (t == 0) {
        __threadfence();           // release
        s_ticket = atomicAdd(&gcnt[gid], 1u);
    }
    __syncthreads();
    if (s_ticket != POISON + (unsigned)(YSPLITS - 1)) return;

    // ---- group leader: this group's 2048 mins are final ----
    __threadfence();               // acquire
    const uint4* vmin = (const uint4*)(mins + (size_t)(pass * B_ + b) * N_ + xbase);
    uint4 q0 = vmin[t];
    uint4 q1 = vmin[THREADS + t];
    float a = sqrtf(__uint_as_float(q0.x)) + sqrtf(__uint_as_float(q0.y))
            + sqrtf(__uint_as_float(q0.z)) + sqrtf(__uint_as_float(q0.w))
            + sqrtf(__uint_as_float(q1.x)) + sqrtf(__uint_as_float(q1.y))
            + sqrtf(__uint_as_float(q1.z)) + sqrtf(__uint_as_float(q1.w));
    red[t] = a;
    __syncthreads();
    for (int off = 128; off > 0; off >>= 1) {
        if (t < off) red[t] += red[t + off];
        __syncthreads();
    }
    if (t == 0) {
        gsum[gid] = red[0];
        __threadfence();           // release
        s_ticket = atomicAdd(fcnt, 1u);
    }
    __syncthreads();
    if (s_ticket != POISON + (unsigned)(NGROUPS - 1)) return;

    // ---- final leader: sum 32 group sums, write the scalar ----
    __threadfence();               // acquire
    red[t] = (t < NGROUPS) ? gsum[t] : 0.0f;
    __syncthreads();
    for (int off = 128; off > 0; off >>= 1) {
        if (t < off) red[t] += red[t + off];
        __syncthreads();
    }
    if (t == 0) out[0] = red[0] * (1.0f / 65536.0f);   // denom = B*(Ng+Np)
}

extern "C" void kernel_launch(void* const* d_in, const int* in_sizes, int n_in,
                              void* d_out, int out_size, void* d_ws, size_t ws_size,
                              hipStream_t stream)
{
    const float* P = (const float*)d_in[0];   // predict_pc [4,3,8192]
    const float* G = (const float*)d_in[1];   // gt_pc      [4,3,8192]
    float* out = (float*)d_out;               // scalar

    unsigned* w    = (unsigned*)d_ws;
    unsigned* mins = w;                       // 65536 words
    unsigned* gcnt = w + 65536;               // 32 words
    unsigned* fcnt = w + 65600;               // 1 word
    float*    gsum = (float*)(w + 65664);     // 32 words

    dim3 grid(XBLKS, YSPLITS, 2 * B_);        // (4, 64, 8) = 2048 wgs
    chamfer_fused_kernel<<<grid, THREADS, 0, stream>>>(P, G, mins, gcnt, fcnt, gsum, out);
}